// Round 1
// baseline (1234.987 us; speedup 1.0000x reference)
//
#include <hip/hip_runtime.h>

#define LRELU_ALPHA 0.2f
#define NEG_INF_V  -9.0e15f

// out[bt][i][o] = elu( sum_j softmax_j( mask(lrelu(Wh1[i]+Wh2[j])) ) * Wh[j][o] )
// Wh = h@W (per bt), Wh1 = Wh@a1, Wh2 = Wh@a2.
//
// One block per (b,t). 512 threads = 8 waves. LDS: Wh (128KB) + Wh1/Wh2 (4KB)
// + union region (17KB: phase-1 transposed h chunk / phase-2 per-wave p-buffers)
// = 152.5 KB (fits gfx950 160KB, 1 block/CU; 192 blocks < 256 CUs).

#define FMA4(d, s, v)                          \
    d.x = fmaf(s, v.x, d.x);                   \
    d.y = fmaf(s, v.y, d.y);                   \
    d.z = fmaf(s, v.z, d.z);                   \
    d.w = fmaf(s, v.w, d.w);

__global__ __launch_bounds__(512)
void gat_fused(const float* __restrict__ h, const float* __restrict__ adj,
               const float* __restrict__ W, const float* __restrict__ a,
               float* __restrict__ out)
{
    __shared__ float sWh[512 * 64];   // Wh[j][o]
    __shared__ float sWh1[512];
    __shared__ float sWh2[512];
    __shared__ float sU[64 * 68];     // phase1: hT[f][68] ; phase2: pbuf[8 waves][512]

    const int tid  = threadIdx.x;
    const int lane = tid & 63;
    const int w    = tid >> 6;          // wave id 0..7
    const int bt   = blockIdx.x;        // 0..191
    const size_t hbase = (size_t)bt * (512 * 64);

    // W column held in registers: lane == o, wreg[f] = W[f][o]
    float wreg[64];
    #pragma unroll
    for (int f = 0; f < 64; ++f) wreg[f] = W[f * 64 + lane];
    const float a1v = a[lane];
    const float a2v = a[64 + lane];

    // ---------------- Phase 1: Wh = h@W, Wh1, Wh2 ----------------
    for (int c = 0; c < 8; ++c) {       // chunks of 64 nodes
        __syncthreads();                // protect sU reuse from previous chunk
        #pragma unroll
        for (int k = 0; k < 8; ++k) {
            int e = k * 512 + tid;      // e = nl*64 + f within chunk
            sU[(e & 63) * 68 + (e >> 6)] = h[hbase + (size_t)c * 4096 + e];
        }
        __syncthreads();

        float acc[8];
        #pragma unroll
        for (int r = 0; r < 8; ++r) acc[r] = 0.f;
        #pragma unroll
        for (int f = 0; f < 64; ++f) {
            float4 hA = *(const float4*)&sU[f * 68 + w * 8];
            float4 hB = *(const float4*)&sU[f * 68 + w * 8 + 4];
            float wv = wreg[f];
            acc[0] = fmaf(hA.x, wv, acc[0]);
            acc[1] = fmaf(hA.y, wv, acc[1]);
            acc[2] = fmaf(hA.z, wv, acc[2]);
            acc[3] = fmaf(hA.w, wv, acc[3]);
            acc[4] = fmaf(hB.x, wv, acc[4]);
            acc[5] = fmaf(hB.y, wv, acc[5]);
            acc[6] = fmaf(hB.z, wv, acc[6]);
            acc[7] = fmaf(hB.w, wv, acc[7]);
        }
        #pragma unroll
        for (int r = 0; r < 8; ++r) {
            int n = c * 64 + w * 8 + r;
            sWh[n * 64 + lane] = acc[r];
            float t1 = acc[r] * a1v;
            float t2 = acc[r] * a2v;
            #pragma unroll
            for (int s = 32; s > 0; s >>= 1) {
                t1 += __shfl_xor(t1, s);
                t2 += __shfl_xor(t2, s);
            }
            if (lane == 0) { sWh1[n] = t1; sWh2[n] = t2; }
        }
    }
    __syncthreads();

    // ---------------- Phase 2: softmax rows + P@Wh ----------------
    float* pbuf = &sU[w * 512];          // per-wave p-buffer [64 j][8 r]
    const int o4 = (lane & 15) * 4;      // this lane's 4 output features
    const int jq = lane >> 4;            // j mod-4 class for the FMA loop
    const size_t obase = (size_t)bt * 32768;

    for (int rb = 0; rb < 8; ++rb) {     // wave w owns rows w*64 .. w*64+63
        const int i0 = w * 64 + rb * 8;

        float wh1[8], m[8], inv[8];
        #pragma unroll
        for (int r = 0; r < 8; ++r) wh1[r] = sWh1[i0 + r];

        // ---- stats: row max and 1/sum(exp) (lanes over j)
        #pragma unroll 1
        for (int r = 0; r < 8; ++r) {
            float att[8];
            float mx = -3.4e38f;
            #pragma unroll
            for (int k = 0; k < 8; ++k) {
                int j = k * 64 + lane;
                float e = wh1[r] + sWh2[j];
                e = (e > 0.f) ? e : LRELU_ALPHA * e;
                float ad = adj[(i0 + r) * 512 + j];
                att[k] = (ad > 0.f) ? e : NEG_INF_V;
                mx = fmaxf(mx, att[k]);
            }
            #pragma unroll
            for (int s = 32; s > 0; s >>= 1) mx = fmaxf(mx, __shfl_xor(mx, s));
            float sum = 0.f;
            #pragma unroll
            for (int k = 0; k < 8; ++k) sum += __expf(att[k] - mx);
            #pragma unroll
            for (int s = 32; s > 0; s >>= 1) sum += __shfl_xor(sum, s);
            m[r] = mx;
            inv[r] = 1.f / sum;
        }

        float4 oacc[8];
        #pragma unroll
        for (int r = 0; r < 8; ++r) oacc[r] = make_float4(0.f, 0.f, 0.f, 0.f);

        #pragma unroll 1
        for (int jb = 0; jb < 8; ++jb) {
            // ---- compute p once per (i,j): lanes over j, 8 rows each
            int j = jb * 64 + lane;
            float wh2j = sWh2[j];
            float pv[8];
            #pragma unroll
            for (int r = 0; r < 8; ++r) {
                float e = wh1[r] + wh2j;
                e = (e > 0.f) ? e : LRELU_ALPHA * e;
                float ad = adj[(i0 + r) * 512 + j];
                pv[r] = (ad > 0.f) ? __expf(e - m[r]) * inv[r] : 0.f;
            }
            *(float4*)&pbuf[lane * 8]     = make_float4(pv[0], pv[1], pv[2], pv[3]);
            *(float4*)&pbuf[lane * 8 + 4] = make_float4(pv[4], pv[5], pv[6], pv[7]);
            // same-wave DS ops are processed in order: no barrier needed
            // (pbuf is private to this wave).

            // ---- accumulate: lane=(o4,jq); Wh read as b128 (4 o's), 4 j's/step
            #pragma unroll
            for (int l = 0; l < 16; ++l) {
                int jl = l * 4 + jq;
                float4 whv = *(const float4*)&sWh[(jb * 64 + jl) * 64 + o4];
                float4 pa  = *(const float4*)&pbuf[jl * 8];
                float4 pb  = *(const float4*)&pbuf[jl * 8 + 4];
                FMA4(oacc[0], pa.x, whv);
                FMA4(oacc[1], pa.y, whv);
                FMA4(oacc[2], pa.z, whv);
                FMA4(oacc[3], pa.w, whv);
                FMA4(oacc[4], pb.x, whv);
                FMA4(oacc[5], pb.y, whv);
                FMA4(oacc[6], pb.z, whv);
                FMA4(oacc[7], pb.w, whv);
            }
        }

        // ---- reduce over jq groups (lane bits 4,5), ELU, store
        #pragma unroll
        for (int r = 0; r < 8; ++r) {
            float4 v = oacc[r];
            #pragma unroll
            for (int s = 16; s <= 32; s <<= 1) {
                v.x += __shfl_xor(v.x, s);
                v.y += __shfl_xor(v.y, s);
                v.z += __shfl_xor(v.z, s);
                v.w += __shfl_xor(v.w, s);
            }
            if (jq == 0) {
                float4 res;
                res.x = (v.x > 0.f) ? v.x : __expf(v.x) - 1.f;
                res.y = (v.y > 0.f) ? v.y : __expf(v.y) - 1.f;
                res.z = (v.z > 0.f) ? v.z : __expf(v.z) - 1.f;
                res.w = (v.w > 0.f) ? v.w : __expf(v.w) - 1.f;
                *(float4*)&out[obase + (size_t)(i0 + r) * 64 + o4] = res;
            }
        }
    }
}

extern "C" void kernel_launch(void* const* d_in, const int* in_sizes, int n_in,
                              void* d_out, int out_size, void* d_ws, size_t ws_size,
                              hipStream_t stream)
{
    const float* h   = (const float*)d_in[0];   // (16,12,512,64)
    const float* adj = (const float*)d_in[1];   // (512,512)
    const float* W   = (const float*)d_in[2];   // (64,64)
    const float* a   = (const float*)d_in[3];   // (128,1)
    float* out = (float*)d_out;                 // (16,12,512,64)

    gat_fused<<<192, 512, 0, stream>>>(h, adj, W, a, out);
}

// Round 2
// 1190.197 us; speedup vs baseline: 1.0376x; 1.0376x over previous
//
#include <hip/hip_runtime.h>

#define LRELU_ALPHA 0.2f
#define NEG_INF_V  -9.0e15f

// out[bt][i][o] = elu( sum_j softmax_j( mask(lrelu(Wh1[i]+Wh2[j])) ) * Wh[j][o] )
// Wh = h@W (per bt), Wh1 = Wh@a1, Wh2 = Wh@a2.
//
// Pre-kernel: adj (512x512 f32) -> bitmask (512 rows x 8 u64) in d_ws.
// Main: one block per (b,t), 512 threads = 8 waves, 1 block/CU (152.5 KB LDS).
// Round-2 changes vs round 1:
//  - NO dynamic indexing of register arrays anywhere (round 1 spilled
//    wh1/m/inv to scratch -> 2.7 GB HBM traffic, 1.2 ms).
//  - single-pass softmax: p[8][8] held in regs; masked entries rely on
//    exp(NEG_INF - m) flushing to 0; fully-masked rows -> uniform (matches ref).
//  - adj read as wave-uniform u64 bitmask words (scalar loads) instead of
//    2 MB of float reads per block.

#define FMA4(d, s, v)                          \
    d.x = fmaf(s, v.x, d.x);                   \
    d.y = fmaf(s, v.y, d.y);                   \
    d.z = fmaf(s, v.z, d.z);                   \
    d.w = fmaf(s, v.w, d.w);

__global__ __launch_bounds__(512)
void adj_bits_kernel(const float* __restrict__ adj, unsigned long long* __restrict__ bits)
{
    const int tid  = threadIdx.x;
    const int lane = tid & 63;
    const int w    = tid >> 6;
    const int g    = blockIdx.x * 8 + w;   // 0..4095
    const int row  = g >> 3;
    const int k    = g & 7;
    float v = adj[row * 512 + k * 64 + lane];
    unsigned long long m = __ballot(v > 0.f);
    if (lane == 0) bits[row * 8 + k] = m;
}

__global__ __launch_bounds__(512, 2)
void gat_fused(const float* __restrict__ h,
               const unsigned long long* __restrict__ bits,
               const float* __restrict__ W, const float* __restrict__ a,
               float* __restrict__ out)
{
    __shared__ float sWh[512 * 64];   // Wh[j][o]
    __shared__ float sWh1[512];
    __shared__ float sWh2[512];
    __shared__ float sU[64 * 68];     // phase1: hT[f][68] ; phase2: pbuf[8 waves][512]

    const int tid  = threadIdx.x;
    const int lane = tid & 63;
    const int w    = tid >> 6;          // wave id 0..7
    const int bt   = blockIdx.x;        // 0..191
    const size_t hbase = (size_t)bt * (512 * 64);

    // W column in registers: lane == o, wreg[f] = W[f][o]
    float wreg[64];
    #pragma unroll
    for (int f = 0; f < 64; ++f) wreg[f] = W[f * 64 + lane];
    const float a1v = a[lane];
    const float a2v = a[64 + lane];

    // ---------------- Phase 1: Wh = h@W, Wh1, Wh2 ----------------
    for (int c = 0; c < 8; ++c) {       // chunks of 64 nodes
        __syncthreads();                // protect sU reuse from previous chunk
        #pragma unroll
        for (int k = 0; k < 8; ++k) {
            int e = k * 512 + tid;      // e = nl*64 + f within chunk
            sU[(e & 63) * 68 + (e >> 6)] = h[hbase + (size_t)c * 4096 + e];
        }
        __syncthreads();

        float acc[8];
        #pragma unroll
        for (int r = 0; r < 8; ++r) acc[r] = 0.f;
        #pragma unroll
        for (int f = 0; f < 64; ++f) {
            float4 hA = *(const float4*)&sU[f * 68 + w * 8];     // wave-uniform (broadcast)
            float4 hB = *(const float4*)&sU[f * 68 + w * 8 + 4];
            float wv = wreg[f];
            acc[0] = fmaf(hA.x, wv, acc[0]);
            acc[1] = fmaf(hA.y, wv, acc[1]);
            acc[2] = fmaf(hA.z, wv, acc[2]);
            acc[3] = fmaf(hA.w, wv, acc[3]);
            acc[4] = fmaf(hB.x, wv, acc[4]);
            acc[5] = fmaf(hB.y, wv, acc[5]);
            acc[6] = fmaf(hB.z, wv, acc[6]);
            acc[7] = fmaf(hB.w, wv, acc[7]);
        }
        #pragma unroll
        for (int r = 0; r < 8; ++r) {
            int n = c * 64 + w * 8 + r;
            sWh[n * 64 + lane] = acc[r];
            float t1 = acc[r] * a1v;
            float t2 = acc[r] * a2v;
            #pragma unroll
            for (int s = 32; s > 0; s >>= 1) {
                t1 += __shfl_xor(t1, s);
                t2 += __shfl_xor(t2, s);
            }
            if (lane == 0) { sWh1[n] = t1; sWh2[n] = t2; }
        }
    }
    __syncthreads();

    // ---------------- Phase 2: softmax rows + P@Wh ----------------
    float* pbuf = &sU[w * 512];          // per-wave p-buffer [64 j][8 r]
    const int o4 = (lane & 15) * 4;      // this lane's 4 output features
    const int jq = lane >> 4;            // j mod-4 class for the FMA loop
    const unsigned long long lmask = 1ull << lane;
    const size_t obase = (size_t)bt * 32768;

    float wh2k[8];
    #pragma unroll
    for (int k = 0; k < 8; ++k) wh2k[k] = sWh2[k * 64 + lane];

    #pragma unroll 1
    for (int rb = 0; rb < 8; ++rb) {     // wave w owns rows w*64 .. w*64+63
        const int i0 = w * 64 + rb * 8;

        // ---- single pass: logits -> stats -> p, all static-indexed regs
        float p[8][8];
        float inv_[8];
        #pragma unroll
        for (int r = 0; r < 8; ++r) {
            const float wh1r = sWh1[i0 + r];
            const unsigned long long* mrow = bits + (size_t)(i0 + r) * 8;
            float mx = NEG_INF_V;
            #pragma unroll
            for (int k = 0; k < 8; ++k) {
                float e = wh1r + wh2k[k];
                e = (e > 0.f) ? e : LRELU_ALPHA * e;
                float av = (mrow[k] & lmask) ? e : NEG_INF_V;
                p[r][k] = av;
                mx = fmaxf(mx, av);
            }
            #pragma unroll
            for (int s = 32; s > 0; s >>= 1) mx = fmaxf(mx, __shfl_xor(mx, s));
            float sum = 0.f;
            #pragma unroll
            for (int k = 0; k < 8; ++k) {
                float ev = __expf(p[r][k] - mx);   // masked: exp(-9e15 - m) -> 0
                p[r][k] = ev;
                sum += ev;
            }
            #pragma unroll
            for (int s = 32; s > 0; s >>= 1) sum += __shfl_xor(sum, s);
            inv_[r] = 1.f / sum;
        }
        #pragma unroll
        for (int r = 0; r < 8; ++r) {
            #pragma unroll
            for (int k = 0; k < 8; ++k) p[r][k] *= inv_[r];
        }

        float4 oacc[8];
        #pragma unroll
        for (int r = 0; r < 8; ++r) oacc[r] = make_float4(0.f, 0.f, 0.f, 0.f);

        #pragma unroll
        for (int jb = 0; jb < 8; ++jb) {
            // p (lanes over j) -> per-wave LDS pbuf; same-wave DS ops are
            // in-order, no barrier needed (pbuf private to this wave).
            *(float4*)&pbuf[lane * 8]     = make_float4(p[0][jb], p[1][jb], p[2][jb], p[3][jb]);
            *(float4*)&pbuf[lane * 8 + 4] = make_float4(p[4][jb], p[5][jb], p[6][jb], p[7][jb]);

            // ---- accumulate: lane=(o4,jq); Wh read as b128 (4 o's), 4 j's/step
            #pragma unroll 2
            for (int l = 0; l < 16; ++l) {
                int jl = l * 4 + jq;
                float4 whv = *(const float4*)&sWh[(jb * 64 + jl) * 64 + o4];
                float4 pa  = *(const float4*)&pbuf[jl * 8];
                float4 pb  = *(const float4*)&pbuf[jl * 8 + 4];
                FMA4(oacc[0], pa.x, whv);
                FMA4(oacc[1], pa.y, whv);
                FMA4(oacc[2], pa.z, whv);
                FMA4(oacc[3], pa.w, whv);
                FMA4(oacc[4], pb.x, whv);
                FMA4(oacc[5], pb.y, whv);
                FMA4(oacc[6], pb.z, whv);
                FMA4(oacc[7], pb.w, whv);
            }
        }

        // ---- reduce over jq groups (lane bits 4,5), ELU, store
        #pragma unroll
        for (int r = 0; r < 8; ++r) {
            float4 v = oacc[r];
            #pragma unroll
            for (int s = 16; s <= 32; s <<= 1) {
                v.x += __shfl_xor(v.x, s);
                v.y += __shfl_xor(v.y, s);
                v.z += __shfl_xor(v.z, s);
                v.w += __shfl_xor(v.w, s);
            }
            if (jq == 0) {
                float4 res;
                res.x = (v.x > 0.f) ? v.x : __expf(v.x) - 1.f;
                res.y = (v.y > 0.f) ? v.y : __expf(v.y) - 1.f;
                res.z = (v.z > 0.f) ? v.z : __expf(v.z) - 1.f;
                res.w = (v.w > 0.f) ? v.w : __expf(v.w) - 1.f;
                *(float4*)&out[obase + (size_t)(i0 + r) * 64 + o4] = res;
            }
        }
    }
}

extern "C" void kernel_launch(void* const* d_in, const int* in_sizes, int n_in,
                              void* d_out, int out_size, void* d_ws, size_t ws_size,
                              hipStream_t stream)
{
    const float* h   = (const float*)d_in[0];   // (16,12,512,64)
    const float* adj = (const float*)d_in[1];   // (512,512)
    const float* W   = (const float*)d_in[2];   // (64,64)
    const float* a   = (const float*)d_in[3];   // (128,1)
    float* out = (float*)d_out;                 // (16,12,512,64)

    unsigned long long* bits = (unsigned long long*)d_ws;  // 512*8*8 B = 32 KB

    adj_bits_kernel<<<512, 512, 0, stream>>>(adj, bits);
    gat_fused<<<192, 512, 0, stream>>>(h, bits, W, a, out);
}